// Round 4
// baseline (1419.542 us; speedup 1.0000x reference)
//
#include <hip/hip_runtime.h>

typedef __bf16 bf16;
typedef float __attribute__((ext_vector_type(4))) f32x4;
typedef __bf16 __attribute__((ext_vector_type(8))) bf16x8;

#define DEVI __device__ __forceinline__

// ---------------- constants ----------------
#define BB 2
#define LL 2048
#define DM 2048
#define HH 16
#define KH 4
#define HD 128
#define NQKV 3072
#define NI 5504
#define TOK 4096            // B*L
#define OUT_ELEMS 8388608   // B*L*D

DEVI f32x4 mfma16(bf16x8 a, bf16x8 b, f32x4 c) {
  return __builtin_amdgcn_mfma_f32_16x16x32_bf16(a, b, c, 0, 0, 0);
}

DEVI void gload16(const void* g, void* l) {
  __builtin_amdgcn_global_load_lds(
      (const __attribute__((address_space(1))) void*)g,
      (__attribute__((address_space(3))) void*)l, 16, 0, 0);
}

// ---------------- canonicalize gen_token_mask to uint8 0/1 ----------------
// Storage format unknown (bool byte / int32 / float32). Detect from first 256
// tokens read as 32-bit words (bytes 0..1023, in-bounds under all formats).
__global__ __launch_bounds__(256)
void canon_mask(const unsigned char* __restrict__ m, unsigned char* __restrict__ outm)
{
  __shared__ int okInt, okFloat;
  const int t = threadIdx.x;
  if (t == 0) { okInt = 1; okFloat = 1; }
  __syncthreads();
  unsigned int w = ((const unsigned int*)m)[t];
  if (!(w == 0u || w == 1u)) atomicAnd(&okInt, 0);
  if (!(w == 0u || w == 0x3F800000u)) atomicAnd(&okFloat, 0);
  __syncthreads();
  const int fmt = okInt ? 1 : (okFloat ? 2 : 0);
  for (int i = t; i < TOK; i += 256) {
    unsigned char v;
    if (fmt == 0) v = (m[i] != 0) ? 1 : 0;
    else          v = (((const unsigned int*)m)[i] != 0u) ? 1 : 0;
    outm[i] = v;
  }
}

// ---------------- weight convert + transpose: f32 [R][C] -> bf16 [C][R] ----------------
__global__ __launch_bounds__(256)
void transpose_f32_bf16(const float* __restrict__ in, bf16* __restrict__ out, int R, int C)
{
  __shared__ float tile[32][33];
  const int tx = threadIdx.x, ty = threadIdx.y;
  const int c0 = blockIdx.x * 32, r0 = blockIdx.y * 32;
#pragma unroll
  for (int i2 = 0; i2 < 4; ++i2) {
    int i = ty + i2 * 8;
    tile[i][tx] = in[(size_t)(r0 + i) * C + c0 + tx];
  }
  __syncthreads();
#pragma unroll
  for (int i2 = 0; i2 < 4; ++i2) {
    int i = ty + i2 * 8;
    out[(size_t)(c0 + i) * R + r0 + tx] = (bf16)tile[tx][i];
  }
}

// ---------------- bf16 transpose per slab: [R][C] -> [C][R] ----------------
__global__ __launch_bounds__(256)
void transpose_bf16_k(const bf16* __restrict__ in, bf16* __restrict__ out, int R, int C)
{
  __shared__ bf16 tile[32][34];
  const int slab = blockIdx.z;
  in  += (size_t)slab * R * C;
  out += (size_t)slab * R * C;
  const int tx = threadIdx.x, ty = threadIdx.y;
  const int c0 = blockIdx.x * 32, r0 = blockIdx.y * 32;
#pragma unroll
  for (int i2 = 0; i2 < 4; ++i2) {
    int i = ty + i2 * 8;
    tile[i][tx] = in[(size_t)(r0 + i) * C + c0 + tx];
  }
  __syncthreads();
#pragma unroll
  for (int i2 = 0; i2 < 4; ++i2) {
    int i = ty + i2 * 8;
    out[(size_t)(c0 + i) * R + r0 + tx] = tile[tx][i];
  }
}

// ---------------- fused add + RMSNorm: res = a+b; h = rmsnorm(res)*w (bf16) ----------------
__global__ __launch_bounds__(256)
void add_rmsnorm(const float* __restrict__ a, const float* __restrict__ bsrc,
                 const float* __restrict__ w, float* __restrict__ res,
                 bf16* __restrict__ h)
{
  const int row = blockIdx.x, t = threadIdx.x;
  const size_t base = (size_t)row * DM + t * 8;
  f32x4 x0 = *(const f32x4*)(a + base);
  f32x4 x1 = *(const f32x4*)(a + base + 4);
  f32x4 y0 = *(const f32x4*)(bsrc + base);
  f32x4 y1 = *(const f32x4*)(bsrc + base + 4);
  x0 += y0; x1 += y1;
  *(f32x4*)(res + base)     = x0;
  *(f32x4*)(res + base + 4) = x1;
  float ss = x0[0]*x0[0] + x0[1]*x0[1] + x0[2]*x0[2] + x0[3]*x0[3]
           + x1[0]*x1[0] + x1[1]*x1[1] + x1[2]*x1[2] + x1[3]*x1[3];
#pragma unroll
  for (int off = 32; off; off >>= 1) ss += __shfl_down(ss, off);
  __shared__ float red[4];
  if ((t & 63) == 0) red[t >> 6] = ss;
  __syncthreads();
  float tot = red[0] + red[1] + red[2] + red[3];
  float scale = rsqrtf(tot * (1.0f / (float)DM) + 1e-6f);
  f32x4 w0 = *(const f32x4*)(w + t * 8);
  f32x4 w1 = *(const f32x4*)(w + t * 8 + 4);
  bf16x8 hv;
#pragma unroll
  for (int i = 0; i < 4; ++i) hv[i]     = (bf16)(x0[i] * scale * w0[i]);
#pragma unroll
  for (int i = 0; i < 4; ++i) hv[i + 4] = (bf16)(x1[i] * scale * w1[i]);
  *(bf16x8*)(h + base) = hv;
}

// ---------------- GEMM: C[M,N] = A[M,K](bf16) @ Bt[N,K](bf16)^T ----------------
// EPI: 0 = f32 store, 2 = bf16 store, 3 = masked f32 store (maskc[row]==want),
//      4 = in-place silu-combine (Cout holds gate bf16; store silu(gate)*v),
//      5 = bf16 store + bias.
template<int EPI>
__global__ __launch_bounds__(256)
void gemm_bt(const bf16* __restrict__ A, const bf16* __restrict__ Bt,
             void* __restrict__ Cout, const float* __restrict__ bias,
             const unsigned char* __restrict__ maskc, int want,
             int M, int N, int K)
{
  __shared__ __align__(16) bf16 As[128 * 64];
  __shared__ __align__(16) bf16 Bs[128 * 64];
  const int tid = threadIdx.x;
  const int lane = tid & 63, w = tid >> 6;
  const int wr = w >> 1, wc = w & 1;
  const int g4 = lane >> 4, r16 = lane & 15;
  const int bm = blockIdx.y * 128, bn = blockIdx.x * 128;

  f32x4 acc[4][4];
#pragma unroll
  for (int m = 0; m < 4; ++m)
#pragma unroll
    for (int n = 0; n < 4; ++n) acc[m][n] = (f32x4){0.f, 0.f, 0.f, 0.f};

  const bf16* Abase = A + (size_t)bm * K;
  const bf16* Bbase = Bt + (size_t)bn * K;

  for (int k0 = 0; k0 < K; k0 += 64) {
    __syncthreads();
#pragma unroll
    for (int r = 0; r < 4; ++r) {
      int idx = r * 256 + tid;
      int row = idx >> 3, ch = idx & 7;
      gload16(Abase + (size_t)row * K + k0 + ((ch ^ (row & 7)) << 3), &As[idx << 3]);
    }
#pragma unroll
    for (int r = 0; r < 4; ++r) {
      int idx = r * 256 + tid;
      int row = idx >> 3, ch = idx & 7;
      gload16(Bbase + (size_t)row * K + k0 + ((ch ^ (row & 7)) << 3), &Bs[idx << 3]);
    }
    __syncthreads();
#pragma unroll
    for (int ks = 0; ks < 2; ++ks) {
      bf16x8 af[4], bfr[4];
#pragma unroll
      for (int m = 0; m < 4; ++m) {
        int row = wr * 64 + m * 16 + r16;
        af[m] = *(const bf16x8*)&As[row * 64 + ((((ks << 2) | g4)) ^ (row & 7)) * 8];
      }
#pragma unroll
      for (int n = 0; n < 4; ++n) {
        int row = wc * 64 + n * 16 + r16;
        bfr[n] = *(const bf16x8*)&Bs[row * 64 + ((((ks << 2) | g4)) ^ (row & 7)) * 8];
      }
#pragma unroll
      for (int m = 0; m < 4; ++m)
#pragma unroll
        for (int n = 0; n < 4; ++n)
          acc[m][n] = mfma16(af[m], bfr[n], acc[m][n]);
    }
  }

#pragma unroll
  for (int m = 0; m < 4; ++m) {
#pragma unroll
    for (int n = 0; n < 4; ++n) {
      int col = bn + wc * 64 + n * 16 + r16;
#pragma unroll
      for (int j = 0; j < 4; ++j) {
        int row = bm + wr * 64 + m * 16 + g4 * 4 + j;
        float v = acc[m][n][j];
        size_t id = (size_t)row * N + col;
        if (EPI == 0) {
          ((float*)Cout)[id] = v;
        } else if (EPI == 2) {
          ((bf16*)Cout)[id] = (bf16)v;
        } else if (EPI == 3) {
          if (maskc[row] == want) ((float*)Cout)[id] = v;
        } else if (EPI == 4) {
          bf16* X = (bf16*)Cout;
          float g = (float)X[id];
          float sv = g / (1.f + __expf(-g));
          X[id] = (bf16)(sv * v);
        } else {
          ((bf16*)Cout)[id] = (bf16)(v + bias[col]);
        }
      }
    }
  }
}

// ---------------- RoPE + split (qkv bf16) ----------------
// qkv bf16 [TOK][3072] -> q bf16 [B,H,L,HD] (pre-scaled by 1/sqrt(HD)),
// k bf16 [B,KH,L,HD], v bf16 [B,KH,L,HD]
__global__ __launch_bounds__(256)
void rope_split(const bf16* __restrict__ qkv, const int* __restrict__ pos,
                bf16* __restrict__ q, bf16* __restrict__ k, bf16* __restrict__ v)
{
  const int bl = blockIdx.x;
  const int slot = blockIdx.y * 4 + (threadIdx.x >> 6);
  const int d = threadIdx.x & 63;
  const int b = bl >> 11, l = bl & 2047;
  const bf16* src;
  if (slot < 16)      src = qkv + (size_t)bl * NQKV + slot * HD;
  else if (slot < 20) src = qkv + (size_t)bl * NQKV + 2048 + (slot - 16) * HD;
  else                src = qkv + (size_t)bl * NQKV + 2560 + (slot - 20) * HD;
  float x1 = (float)src[d], x2 = (float)src[d + 64];
  if (slot < 20) {
    float p = (float)pos[bl];
    float invf = __expf((float)d * -0.21586735246819177f);  // ln(1e6)/64
    float fr = p * invf;
    float s, c;
    __sincosf(fr, &s, &c);
    float o1 = x1 * c - x2 * s;
    float o2 = x2 * c + x1 * s;
    if (slot < 16) {
      o1 *= 0.08838834764831845f; o2 *= 0.08838834764831845f;  // 1/sqrt(128)
      bf16* dst = q + ((size_t)(b * HH + slot) * LL + l) * HD;
      dst[d] = (bf16)o1; dst[d + 64] = (bf16)o2;
    } else {
      bf16* dst = k + ((size_t)(b * KH + (slot - 16)) * LL + l) * HD;
      dst[d] = (bf16)o1; dst[d + 64] = (bf16)o2;
    }
  } else {
    bf16* dst = v + ((size_t)(b * KH + (slot - 20)) * LL + l) * HD;
    dst[d] = (bf16)x1; dst[d + 64] = (bf16)x2;
  }
}

// ---------------- causal GQA flash attention ----------------
__global__ __launch_bounds__(256)
void attn_kernel(const bf16* __restrict__ Q, const bf16* __restrict__ Kr,
                 const bf16* __restrict__ Vt, bf16* __restrict__ O)
{
  __shared__ __align__(16) bf16 Ks[64 * 128];
  __shared__ __align__(16) bf16 Vs[128 * 64];
  __shared__ __align__(16) bf16 Pl[4][16 * 64];
  const int tid = threadIdx.x, lane = tid & 63, w = tid >> 6;
  const int g4 = lane >> 4, r16 = lane & 15;
  const int qt = blockIdx.x;
  const int bh = blockIdx.y;              // b*H + h
  const int b = bh >> 4, h = bh & 15;
  const int kh = h >> 2;
  const int qbase = qt * 64 + w * 16;

  const bf16* Qp = Q + ((size_t)bh * LL + qbase) * HD;
  const bf16* Kp = Kr + ((size_t)(b * KH + kh) * LL) * HD;
  const bf16* Vp = Vt + ((size_t)(b * KH + kh) * HD) * LL;

  bf16x8 qf[4];
#pragma unroll
  for (int ks = 0; ks < 4; ++ks)
    qf[ks] = *(const bf16x8*)(Qp + (size_t)r16 * HD + ks * 32 + g4 * 8);

  f32x4 acc_o[8];
#pragma unroll
  for (int i = 0; i < 8; ++i) acc_o[i] = (f32x4){0.f, 0.f, 0.f, 0.f};
  float mrow[4], lrow[4];
#pragma unroll
  for (int j = 0; j < 4; ++j) { mrow[j] = -3.0e38f; lrow[j] = 0.f; }

  const int nch = qt + 1;
  for (int c = 0; c < nch; ++c) {
    const int kv0 = c * 64;
    __syncthreads();
#pragma unroll
    for (int r = 0; r < 4; ++r) {
      int idx = r * 256 + tid;
      int row = idx >> 4, ch = idx & 15;
      gload16(Kp + (size_t)(kv0 + row) * HD + ((ch ^ (row & 7)) << 3), &Ks[idx << 3]);
    }
#pragma unroll
    for (int r = 0; r < 4; ++r) {
      int idx = r * 256 + tid;
      int row = idx >> 3, ch = idx & 7;
      gload16(Vp + (size_t)row * LL + kv0 + ((ch ^ (row & 7)) << 3), &Vs[idx << 3]);
    }
    __syncthreads();

    f32x4 sacc[4];
#pragma unroll
    for (int nf = 0; nf < 4; ++nf) {
      sacc[nf] = (f32x4){0.f, 0.f, 0.f, 0.f};
#pragma unroll
      for (int ks = 0; ks < 4; ++ks) {
        int row = nf * 16 + r16;
        bf16x8 kf = *(const bf16x8*)&Ks[row * 128 + ((((ks << 2) | g4)) ^ (row & 7)) * 8];
        sacc[nf] = mfma16(qf[ks], kf, sacc[nf]);
      }
    }
    if (kv0 + 63 > qbase) {
#pragma unroll
      for (int nf = 0; nf < 4; ++nf) {
        int kv = kv0 + nf * 16 + r16;
#pragma unroll
        for (int j = 0; j < 4; ++j) {
          int qq = qbase + g4 * 4 + j;
          if (kv > qq) sacc[nf][j] = -3.0e38f;
        }
      }
    }
#pragma unroll
    for (int j = 0; j < 4; ++j) {
      float v = fmaxf(fmaxf(sacc[0][j], sacc[1][j]), fmaxf(sacc[2][j], sacc[3][j]));
      v = fmaxf(v, __shfl_xor(v, 1));
      v = fmaxf(v, __shfl_xor(v, 2));
      v = fmaxf(v, __shfl_xor(v, 4));
      v = fmaxf(v, __shfl_xor(v, 8));
      float mn = fmaxf(mrow[j], v);
      float f = __expf(mrow[j] - mn);
      mrow[j] = mn;
      float rs = 0.f;
#pragma unroll
      for (int nf = 0; nf < 4; ++nf) {
        float p = __expf(sacc[nf][j] - mn);
        sacc[nf][j] = p;
        rs += p;
      }
      rs += __shfl_xor(rs, 1);
      rs += __shfl_xor(rs, 2);
      rs += __shfl_xor(rs, 4);
      rs += __shfl_xor(rs, 8);
      lrow[j] = lrow[j] * f + rs;
#pragma unroll
      for (int nf = 0; nf < 8; ++nf) acc_o[nf][j] *= f;
    }
    bf16* pw = &Pl[w][0];
#pragma unroll
    for (int nf = 0; nf < 4; ++nf) {
#pragma unroll
      for (int j = 0; j < 4; ++j) {
        int qq = g4 * 4 + j;
        int kv = nf * 16 + r16;
        pw[qq * 64 + (kv ^ ((qq & 7) << 3))] = (bf16)sacc[nf][j];
      }
    }
    __syncthreads();
#pragma unroll
    for (int ks2 = 0; ks2 < 2; ++ks2) {
      int qrow = r16;
      bf16x8 pf = *(const bf16x8*)&pw[qrow * 64 + ((((ks2 << 2) | g4)) ^ (qrow & 7)) * 8];
#pragma unroll
      for (int nf = 0; nf < 8; ++nf) {
        int row = nf * 16 + r16;
        bf16x8 vf = *(const bf16x8*)&Vs[row * 64 + ((((ks2 << 2) | g4)) ^ (row & 7)) * 8];
        acc_o[nf] = mfma16(pf, vf, acc_o[nf]);
      }
    }
  }
#pragma unroll
  for (int nf = 0; nf < 8; ++nf) {
    int d = nf * 16 + r16;
#pragma unroll
    for (int j = 0; j < 4; ++j) {
      int qq = qbase + g4 * 4 + j;
      int token = b * LL + qq;
      O[(size_t)token * (HH * HD) + h * HD + d] = (bf16)(acc_o[nf][j] / lrow[j]);
    }
  }
}

// ---------------- launch ----------------
// Workspace layout, peak 134.2 MB (phases alias; all offsets in bytes):
//   maskc : 0          (4 KB)
//   h2    : 4096       (16,777,216)
//   R = 16,781,312 — shared phase-A / phase-B region:
//   phase A: res1 f32 @R+0 (33.5M, dies at rmsnorm2) | hbuf @R+33.6M (16.8M,
//     dies after QKV gemm; reused as attnb) | wqkvT @R+50.3M (12.6M, reused as
//     woT) | qkvb bf16 @R+62.9M (25.2M, dies at rope_split) | qr @R+88.1M
//     (16.8M) | kr @R+104.9M (4.2M) | vtmp @R+109.1M | vT @R+113.2M (end
//     R+117.4M).  obuf f32 @R+62.9M (33.5M, overlays dead qkvb+qr-head).
//   phase B (after rmsnorm2, all of R dead): guT @R+0 (45.1M) | dT @R+45.1M
//     (22.5M) | X @R+67.6M (45.1M, end R+112.7M).
extern "C" void kernel_launch(void* const* d_in, const int* in_sizes, int n_in,
                              void* d_out, int out_size, void* d_ws, size_t ws_size,
                              hipStream_t stream) {
  (void)in_sizes; (void)n_in; (void)out_size; (void)ws_size;
  const int*   positions = (const int*)d_in[0];
  const float* hidden    = (const float*)d_in[1];
  const float* residual  = (const float*)d_in[2];
  const unsigned char* mask_raw = (const unsigned char*)d_in[3];
  const float* w_in_ln   = (const float*)d_in[4];
  const float* w_post_ln = (const float*)d_in[5];
  const float* wqkv      = (const float*)d_in[6];
  const float* bqkv      = (const float*)d_in[7];
  const float* wo        = (const float*)d_in[8];
  const float* mlp_gate  = (const float*)d_in[9];
  const float* mlp_up    = (const float*)d_in[10];
  const float* mlp_down  = (const float*)d_in[11];
  const float* gen_gate  = (const float*)d_in[12];
  const float* gen_up    = (const float*)d_in[13];
  const float* gen_down  = (const float*)d_in[14];
  float* out_f = (float*)d_out;
  float* res2_out = out_f + OUT_ELEMS;

  char* wsb = (char*)d_ws;
  unsigned char* maskc = (unsigned char*)wsb;               // 4 KB
  bf16*  h2  = (bf16*)(wsb + 4096);                         // 16,777,216
  char*  R   = wsb + 16781312;
  // phase A
  float* res1  = (float*)(R);                               // 33,554,432
  bf16*  hbuf  = (bf16*)(R + 33554432);                     // 16,777,216
  bf16*  wqkvT = (bf16*)(R + 50331648);                     // 12,582,912
  bf16*  qkvb  = (bf16*)(R + 62914560);                     // 25,165,824
  bf16*  qr    = (bf16*)(R + 88080384);                     // 16,777,216
  bf16*  kr    = (bf16*)(R + 104857600);                    //  4,194,304
  bf16*  vtmp  = (bf16*)(R + 109051904);                    //  4,194,304
  bf16*  vT    = (bf16*)(R + 113246208);                    //  4,194,304 -> end R+117,440,512
  bf16*  attnb = hbuf;          // hbuf dead after QKV GEMM
  bf16*  woT   = wqkvT;         // wqkvT dead after QKV GEMM
  float* obuf  = (float*)(R + 62914560);  // overlays dead qkvb + head of dead qr
  // phase B
  bf16* guT = (bf16*)(R);                                   // 45,088,768 (gate^T | up^T)
  bf16* dT  = (bf16*)(R + 45088768);                        // 22,544,384
  bf16* X   = (bf16*)(R + 67633152);                        // 45,088,768 -> end R+112,721,920

  dim3 tb(32, 8);

  // ---- mask canonicalization ----
  canon_mask<<<1, 256, 0, stream>>>(mask_raw, maskc);

  // ---- phase A ----
  add_rmsnorm<<<TOK, 256, 0, stream>>>(hidden, residual, w_in_ln, res1, hbuf);
  transpose_f32_bf16<<<dim3(NQKV / 32, DM / 32), tb, 0, stream>>>(wqkv, wqkvT, DM, NQKV);
  gemm_bt<5><<<dim3(NQKV / 128, TOK / 128), 256, 0, stream>>>(
      hbuf, wqkvT, qkvb, bqkv, nullptr, 0, TOK, NQKV, DM);
  rope_split<<<dim3(TOK, 6), 256, 0, stream>>>(qkvb, positions, qr, kr, vtmp);
  transpose_bf16_k<<<dim3(HD / 32, LL / 32, BB * KH), tb, 0, stream>>>(vtmp, vT, LL, HD);
  attn_kernel<<<dim3(LL / 64, BB * HH), 256, 0, stream>>>(qr, kr, vT, attnb);
  transpose_f32_bf16<<<dim3(DM / 32, DM / 32), tb, 0, stream>>>(wo, woT, DM, DM);
  gemm_bt<0><<<dim3(DM / 128, TOK / 128), 256, 0, stream>>>(
      attnb, woT, obuf, nullptr, nullptr, 0, TOK, DM, DM);
  add_rmsnorm<<<TOK, 256, 0, stream>>>(obuf, res1, w_post_ln, res2_out, h2);

  // ---- phase B: underlying MLP ----
  transpose_f32_bf16<<<dim3(NI / 32, DM / 32), tb, 0, stream>>>(mlp_gate, guT, DM, NI);
  transpose_f32_bf16<<<dim3(NI / 32, DM / 32), tb, 0, stream>>>(mlp_up, guT + (size_t)NI * DM, DM, NI);
  transpose_f32_bf16<<<dim3(DM / 32, NI / 32), tb, 0, stream>>>(mlp_down, dT, NI, DM);
  gemm_bt<2><<<dim3(NI / 128, TOK / 128), 256, 0, stream>>>(
      h2, guT, X, nullptr, nullptr, 0, TOK, NI, DM);
  gemm_bt<4><<<dim3(NI / 128, TOK / 128), 256, 0, stream>>>(
      h2, guT + (size_t)NI * DM, X, nullptr, nullptr, 0, TOK, NI, DM);
  gemm_bt<3><<<dim3(DM / 128, TOK / 128), 256, 0, stream>>>(
      X, dT, out_f, nullptr, maskc, 0, TOK, DM, NI);

  // ---- phase B: gen MLP (reuse weight buffers; stream-ordered) ----
  transpose_f32_bf16<<<dim3(NI / 32, DM / 32), tb, 0, stream>>>(gen_gate, guT, DM, NI);
  transpose_f32_bf16<<<dim3(NI / 32, DM / 32), tb, 0, stream>>>(gen_up, guT + (size_t)NI * DM, DM, NI);
  transpose_f32_bf16<<<dim3(DM / 32, NI / 32), tb, 0, stream>>>(gen_down, dT, NI, DM);
  gemm_bt<2><<<dim3(NI / 128, TOK / 128), 256, 0, stream>>>(
      h2, guT, X, nullptr, nullptr, 0, TOK, NI, DM);
  gemm_bt<4><<<dim3(NI / 128, TOK / 128), 256, 0, stream>>>(
      h2, guT + (size_t)NI * DM, X, nullptr, nullptr, 0, TOK, NI, DM);
  gemm_bt<3><<<dim3(DM / 128, TOK / 128), 256, 0, stream>>>(
      X, dT, out_f, nullptr, maskc, 1, TOK, DM, NI);
}

// Round 5
// 1128.596 us; speedup vs baseline: 1.2578x; 1.2578x over previous
//
#include <hip/hip_runtime.h>

typedef __bf16 bf16;
typedef float __attribute__((ext_vector_type(4))) f32x4;
typedef __bf16 __attribute__((ext_vector_type(8))) bf16x8;

#define DEVI __device__ __forceinline__

// ---------------- constants ----------------
#define BB 2
#define LL 2048
#define DM 2048
#define HH 16
#define KH 4
#define HD 128
#define NQKV 3072
#define NI 5504
#define TOK 4096            // B*L
#define OUT_ELEMS 8388608   // B*L*D
#define NT 32               // LL/64 q-tiles

DEVI f32x4 mfma16(bf16x8 a, bf16x8 b, f32x4 c) {
  return __builtin_amdgcn_mfma_f32_16x16x32_bf16(a, b, c, 0, 0, 0);
}

DEVI void gload16(const void* g, void* l) {
  __builtin_amdgcn_global_load_lds(
      (const __attribute__((address_space(1))) void*)g,
      (__attribute__((address_space(3))) void*)l, 16, 0, 0);
}

// ---------------- mask scan: canon + prefix + inverse permutations ----------------
// Detect storage (bool byte / int32 / float32) from first 256 32-bit words
// (bytes 0..1023, in-bounds under all formats; proven working in round 4).
// Outputs: inv0[i] = token of i-th mask==0 row, inv1 likewise for mask==1,
// cnts = {c0, c0_pad128, c1, c1_pad128}; pad entries of inv point to token 0.
__global__ __launch_bounds__(256)
void mask_scan(const unsigned char* __restrict__ m,
               int* __restrict__ inv0, int* __restrict__ inv1,
               int* __restrict__ cnts)
{
  __shared__ int okInt, okFloat;
  __shared__ int wsum[4];
  const int t = threadIdx.x;
  if (t == 0) { okInt = 1; okFloat = 1; }
  __syncthreads();
  unsigned int wdet = ((const unsigned int*)m)[t];
  if (!(wdet == 0u || wdet == 1u)) atomicAnd(&okInt, 0);
  if (!(wdet == 0u || wdet == 0x3F800000u)) atomicAnd(&okFloat, 0);
  __syncthreads();
  const int fmt = okInt ? 1 : (okFloat ? 2 : 0);
  int bits[16], s1 = 0;
#pragma unroll
  for (int k = 0; k < 16; ++k) {
    int i = t * 16 + k;
    int v = (fmt == 0) ? (m[i] != 0) : (((const unsigned int*)m)[i] != 0u);
    bits[k] = v; s1 += v;
  }
  int x = s1;
#pragma unroll
  for (int off = 1; off < 64; off <<= 1) {
    int y = __shfl_up(x, off);
    if ((t & 63) >= off) x += y;
  }
  if ((t & 63) == 63) wsum[t >> 6] = x;
  __syncthreads();
  int woff = 0;
  for (int u = 0; u < (t >> 6); ++u) woff += wsum[u];
  int tot = wsum[0] + wsum[1] + wsum[2] + wsum[3];
  int excl1 = woff + x - s1;        // ones before this thread's tokens
  int excl0 = t * 16 - excl1;       // zeros before
  int idx0 = excl0, idx1 = excl1;
#pragma unroll
  for (int k = 0; k < 16; ++k) {
    int i = t * 16 + k;
    if (bits[k]) inv1[idx1++] = i; else inv0[idx0++] = i;
  }
  int c1 = tot, c0 = TOK - tot;
  int c0p = (c0 + 127) & ~127, c1p = (c1 + 127) & ~127;
  if (t == 0) { cnts[0] = c0; cnts[1] = c0p; cnts[2] = c1; cnts[3] = c1p; }
  for (int i = c0 + t; i < c0p; i += 256) inv0[i] = 0;
  for (int i = c1 + t; i < c1p; i += 256) inv1[i] = 0;
}

// ---------------- weight convert + transpose: f32 [R][C] -> bf16 [C][R] ----------------
__global__ __launch_bounds__(256)
void transpose_f32_bf16(const float* __restrict__ in, bf16* __restrict__ out, int R, int C)
{
  __shared__ float tile[32][33];
  const int tx = threadIdx.x, ty = threadIdx.y;
  const int c0 = blockIdx.x * 32, r0 = blockIdx.y * 32;
#pragma unroll
  for (int i2 = 0; i2 < 4; ++i2) {
    int i = ty + i2 * 8;
    tile[i][tx] = in[(size_t)(r0 + i) * C + c0 + tx];
  }
  __syncthreads();
#pragma unroll
  for (int i2 = 0; i2 < 4; ++i2) {
    int i = ty + i2 * 8;
    out[(size_t)(c0 + i) * R + r0 + tx] = (bf16)tile[tx][i];
  }
}

// ---------------- bf16 transpose per slab: [R][C] -> [C][R] ----------------
__global__ __launch_bounds__(256)
void transpose_bf16_k(const bf16* __restrict__ in, bf16* __restrict__ out, int R, int C)
{
  __shared__ bf16 tile[32][34];
  const int slab = blockIdx.z;
  in  += (size_t)slab * R * C;
  out += (size_t)slab * R * C;
  const int tx = threadIdx.x, ty = threadIdx.y;
  const int c0 = blockIdx.x * 32, r0 = blockIdx.y * 32;
#pragma unroll
  for (int i2 = 0; i2 < 4; ++i2) {
    int i = ty + i2 * 8;
    tile[i][tx] = in[(size_t)(r0 + i) * C + c0 + tx];
  }
  __syncthreads();
#pragma unroll
  for (int i2 = 0; i2 < 4; ++i2) {
    int i = ty + i2 * 8;
    out[(size_t)(c0 + i) * R + r0 + tx] = tile[tx][i];
  }
}

// ---------------- fused add + RMSNorm ----------------
__global__ __launch_bounds__(256)
void add_rmsnorm(const float* __restrict__ a, const float* __restrict__ bsrc,
                 const float* __restrict__ w, float* __restrict__ res,
                 bf16* __restrict__ h)
{
  const int row = blockIdx.x, t = threadIdx.x;
  const size_t base = (size_t)row * DM + t * 8;
  f32x4 x0 = *(const f32x4*)(a + base);
  f32x4 x1 = *(const f32x4*)(a + base + 4);
  f32x4 y0 = *(const f32x4*)(bsrc + base);
  f32x4 y1 = *(const f32x4*)(bsrc + base + 4);
  x0 += y0; x1 += y1;
  *(f32x4*)(res + base)     = x0;
  *(f32x4*)(res + base + 4) = x1;
  float ss = x0[0]*x0[0] + x0[1]*x0[1] + x0[2]*x0[2] + x0[3]*x0[3]
           + x1[0]*x1[0] + x1[1]*x1[1] + x1[2]*x1[2] + x1[3]*x1[3];
#pragma unroll
  for (int off = 32; off; off >>= 1) ss += __shfl_down(ss, off);
  __shared__ float red[4];
  if ((t & 63) == 0) red[t >> 6] = ss;
  __syncthreads();
  float tot = red[0] + red[1] + red[2] + red[3];
  float scale = rsqrtf(tot * (1.0f / (float)DM) + 1e-6f);
  f32x4 w0 = *(const f32x4*)(w + t * 8);
  f32x4 w1 = *(const f32x4*)(w + t * 8 + 4);
  bf16x8 hv;
#pragma unroll
  for (int i = 0; i < 4; ++i) hv[i]     = (bf16)(x0[i] * scale * w0[i]);
#pragma unroll
  for (int i = 0; i < 4; ++i) hv[i + 4] = (bf16)(x1[i] * scale * w1[i]);
  *(bf16x8*)(h + base) = hv;
}

// ---------------- GEMM: C[M,N] = A[M,K](bf16) @ Bt[N,K](bf16)^T ----------------
// EPI: 0 = f32 store, 2 = bf16 store, 4 = in-place silu-combine
//      (Cout holds gate bf16; store silu(gate)*v), 5 = bf16 store + bias,
//      6 = scatter f32: row r -> out[inv[r]] for r < cnt2[0].
// IA = 1: indirect A rows: global row of compacted row r is inv[r].
// cnt2 != nullptr: early-exit M-tiles with bm >= cnt2[1] (padded count).
template<int EPI, int IA>
__global__ __launch_bounds__(256)
void gemm_bt(const bf16* __restrict__ A, const bf16* __restrict__ Bt,
             void* __restrict__ Cout, const float* __restrict__ bias,
             const int* __restrict__ inv, const int* __restrict__ cnt2,
             int M, int N, int K)
{
  const int bm = blockIdx.y * 128, bn = blockIdx.x * 128;
  if (cnt2 && bm >= cnt2[1]) return;
  __shared__ __align__(16) bf16 As[128 * 64];
  __shared__ __align__(16) bf16 Bs[128 * 64];
  const int tid = threadIdx.x;
  const int lane = tid & 63, w = tid >> 6;
  const int wr = w >> 1, wc = w & 1;
  const int g4 = lane >> 4, r16 = lane & 15;

  size_t arow[4];
#pragma unroll
  for (int r = 0; r < 4; ++r) {
    int row = (r * 256 + tid) >> 3;
    int tok = IA ? inv[bm + row] : (bm + row);
    arow[r] = (size_t)tok * K;
  }

  f32x4 acc[4][4];
#pragma unroll
  for (int m = 0; m < 4; ++m)
#pragma unroll
    for (int n = 0; n < 4; ++n) acc[m][n] = (f32x4){0.f, 0.f, 0.f, 0.f};

  const bf16* Bbase = Bt + (size_t)bn * K;

  for (int k0 = 0; k0 < K; k0 += 64) {
    __syncthreads();
#pragma unroll
    for (int r = 0; r < 4; ++r) {
      int idx = r * 256 + tid;
      int row = idx >> 3, ch = idx & 7;
      gload16(A + arow[r] + k0 + ((ch ^ (row & 7)) << 3), &As[idx << 3]);
    }
#pragma unroll
    for (int r = 0; r < 4; ++r) {
      int idx = r * 256 + tid;
      int row = idx >> 3, ch = idx & 7;
      gload16(Bbase + (size_t)row * K + k0 + ((ch ^ (row & 7)) << 3), &Bs[idx << 3]);
    }
    __syncthreads();
#pragma unroll
    for (int ks = 0; ks < 2; ++ks) {
      bf16x8 af[4], bfr[4];
#pragma unroll
      for (int m = 0; m < 4; ++m) {
        int row = wr * 64 + m * 16 + r16;
        af[m] = *(const bf16x8*)&As[row * 64 + ((((ks << 2) | g4)) ^ (row & 7)) * 8];
      }
#pragma unroll
      for (int n = 0; n < 4; ++n) {
        int row = wc * 64 + n * 16 + r16;
        bfr[n] = *(const bf16x8*)&Bs[row * 64 + ((((ks << 2) | g4)) ^ (row & 7)) * 8];
      }
#pragma unroll
      for (int m = 0; m < 4; ++m)
#pragma unroll
        for (int n = 0; n < 4; ++n)
          acc[m][n] = mfma16(af[m], bfr[n], acc[m][n]);
    }
  }

  const int cnt = (EPI == 6) ? cnt2[0] : 0;
#pragma unroll
  for (int m = 0; m < 4; ++m) {
#pragma unroll
    for (int n = 0; n < 4; ++n) {
      int col = bn + wc * 64 + n * 16 + r16;
#pragma unroll
      for (int j = 0; j < 4; ++j) {
        int row = bm + wr * 64 + m * 16 + g4 * 4 + j;
        float v = acc[m][n][j];
        size_t id = (size_t)row * N + col;
        if (EPI == 0) {
          ((float*)Cout)[id] = v;
        } else if (EPI == 2) {
          ((bf16*)Cout)[id] = (bf16)v;
        } else if (EPI == 4) {
          bf16* X = (bf16*)Cout;
          float g = (float)X[id];
          float sv = g / (1.f + __expf(-g));
          X[id] = (bf16)(sv * v);
        } else if (EPI == 5) {
          ((bf16*)Cout)[id] = (bf16)(v + bias[col]);
        } else {
          if (row < cnt)
            ((float*)Cout)[(size_t)inv[row] * N + col] = v;
        }
      }
    }
  }
}

// ---------------- RoPE + split (qkv bf16) ----------------
__global__ __launch_bounds__(256)
void rope_split(const bf16* __restrict__ qkv, const int* __restrict__ pos,
                bf16* __restrict__ q, bf16* __restrict__ k, bf16* __restrict__ v)
{
  const int bl = blockIdx.x;
  const int slot = blockIdx.y * 4 + (threadIdx.x >> 6);
  const int d = threadIdx.x & 63;
  const int b = bl >> 11, l = bl & 2047;
  const bf16* src;
  if (slot < 16)      src = qkv + (size_t)bl * NQKV + slot * HD;
  else if (slot < 20) src = qkv + (size_t)bl * NQKV + 2048 + (slot - 16) * HD;
  else                src = qkv + (size_t)bl * NQKV + 2560 + (slot - 20) * HD;
  float x1 = (float)src[d], x2 = (float)src[d + 64];
  if (slot < 20) {
    float p = (float)pos[bl];
    float invf = __expf((float)d * -0.21586735246819177f);  // ln(1e6)/64
    float fr = p * invf;
    float s, c;
    __sincosf(fr, &s, &c);
    float o1 = x1 * c - x2 * s;
    float o2 = x2 * c + x1 * s;
    if (slot < 16) {
      o1 *= 0.08838834764831845f; o2 *= 0.08838834764831845f;  // 1/sqrt(128)
      bf16* dst = q + ((size_t)(b * HH + slot) * LL + l) * HD;
      dst[d] = (bf16)o1; dst[d + 64] = (bf16)o2;
    } else {
      bf16* dst = k + ((size_t)(b * KH + (slot - 16)) * LL + l) * HD;
      dst[d] = (bf16)o1; dst[d + 64] = (bf16)o2;
    }
  } else {
    bf16* dst = v + ((size_t)(b * KH + (slot - 20)) * LL + l) * HD;
    dst[d] = (bf16)x1; dst[d + 64] = (bf16)x2;
  }
}

// ---------------- causal GQA flash attention v2 ----------------
// Paired q-tiles (qt, NT-1-qt) per block -> uniform 33 chunks/block.
// Double-buffered K/V staging; raw s_barrier + counted vmcnt(8) keeps the
// next chunk's global_load_lds in flight across the barrier (T3/T4 pattern).
// Pl is wave-private -> no barrier between P write and PV read (lgkmcnt only).
__global__ __launch_bounds__(256)
void attn_kernel(const bf16* __restrict__ Q, const bf16* __restrict__ Kr,
                 const bf16* __restrict__ Vt, bf16* __restrict__ O)
{
  __shared__ __align__(16) bf16 Ks[2][64 * 128];
  __shared__ __align__(16) bf16 Vs[2][128 * 64];
  __shared__ __align__(16) bf16 Pl[4][16 * 64];
  const int tid = threadIdx.x, lane = tid & 63, w = tid >> 6;
  const int g4 = lane >> 4, r16 = lane & 15;
  const int bh = blockIdx.y;              // b*H + h
  const int b = bh >> 4, h = bh & 15;
  const int kh = h >> 2;
  const int qt0 = blockIdx.x;             // 0..15
  const int qt1 = NT - 1 - qt0;           // 31..16
  const int nch0 = qt0 + 1;
  const int total = nch0 + qt1 + 1;       // 33

  const bf16* Kp = Kr + ((size_t)(b * KH + kh) * LL) * HD;
  const bf16* Vp = Vt + ((size_t)(b * KH + kh) * HD) * LL;

  auto stage = [&](int buf, int c) {
    const int kv0 = c * 64;
    bf16* ks = &Ks[buf][0];
    bf16* vs = &Vs[buf][0];
#pragma unroll
    for (int r = 0; r < 4; ++r) {
      int idx = r * 256 + tid;
      int row = idx >> 4, ch = idx & 15;
      gload16(Kp + (size_t)(kv0 + row) * HD + ((ch ^ (row & 7)) << 3), &ks[idx << 3]);
    }
#pragma unroll
    for (int r = 0; r < 4; ++r) {
      int idx = r * 256 + tid;
      int row = idx >> 3, ch = idx & 7;
      gload16(Vp + (size_t)row * LL + kv0 + ((ch ^ (row & 7)) << 3), &vs[idx << 3]);
    }
  };

  int qbase = qt0 * 64 + w * 16;
  const bf16* Qp = Q + ((size_t)bh * LL + qbase) * HD;
  bf16x8 qf[4];
#pragma unroll
  for (int ks = 0; ks < 4; ++ks)
    qf[ks] = *(const bf16x8*)(Qp + (size_t)r16 * HD + ks * 32 + g4 * 8);

  f32x4 acc_o[8];
#pragma unroll
  for (int i = 0; i < 8; ++i) acc_o[i] = (f32x4){0.f, 0.f, 0.f, 0.f};
  float mrow[4], lrow[4];
#pragma unroll
  for (int j = 0; j < 4; ++j) { mrow[j] = -3.0e38f; lrow[j] = 0.f; }

  auto epilogue = [&](int qb) {
    float rl[4];
#pragma unroll
    for (int j = 0; j < 4; ++j) rl[j] = __builtin_amdgcn_rcpf(lrow[j]);
#pragma unroll
    for (int nf = 0; nf < 8; ++nf) {
      int d = nf * 16 + r16;
#pragma unroll
      for (int j = 0; j < 4; ++j) {
        int qq = qb + g4 * 4 + j;
        int token = b * LL + qq;
        O[(size_t)token * (HH * HD) + h * HD + d] = (bf16)(acc_o[nf][j] * rl[j]);
      }
    }
  };

  stage(0, 0);
  int cur = 0;
  for (int i = 0; i < total; ++i) {
    if (i + 1 < total) {
      int nc = (i + 1 < nch0) ? (i + 1) : (i + 1 - nch0);
      stage(cur ^ 1, nc);
      asm volatile("s_waitcnt vmcnt(8)" ::: "memory");
    } else {
      asm volatile("s_waitcnt vmcnt(0)" ::: "memory");
    }
    __builtin_amdgcn_s_barrier();

    if (i == nch0) {
      // finish tile 0, switch to tile 1
      epilogue(qt0 * 64 + w * 16);
      qbase = qt1 * 64 + w * 16;
      const bf16* Qp1 = Q + ((size_t)bh * LL + qbase) * HD;
#pragma unroll
      for (int ks = 0; ks < 4; ++ks)
        qf[ks] = *(const bf16x8*)(Qp1 + (size_t)r16 * HD + ks * 32 + g4 * 8);
#pragma unroll
      for (int z = 0; z < 8; ++z) acc_o[z] = (f32x4){0.f, 0.f, 0.f, 0.f};
#pragma unroll
      for (int j = 0; j < 4; ++j) { mrow[j] = -3.0e38f; lrow[j] = 0.f; }
    }
    const int c = (i < nch0) ? i : (i - nch0);
    const int kv0 = c * 64;
    const bf16* ksb = &Ks[cur][0];
    const bf16* vsb = &Vs[cur][0];

    f32x4 sacc[4];
#pragma unroll
    for (int nf = 0; nf < 4; ++nf) {
      sacc[nf] = (f32x4){0.f, 0.f, 0.f, 0.f};
#pragma unroll
      for (int ks = 0; ks < 4; ++ks) {
        int row = nf * 16 + r16;
        bf16x8 kf = *(const bf16x8*)&ksb[row * 128 + ((((ks << 2) | g4)) ^ (row & 7)) * 8];
        sacc[nf] = mfma16(qf[ks], kf, sacc[nf]);
      }
    }
    if (kv0 + 63 > qbase) {
#pragma unroll
      for (int nf = 0; nf < 4; ++nf) {
        int kv = kv0 + nf * 16 + r16;
#pragma unroll
        for (int j = 0; j < 4; ++j) {
          int qq = qbase + g4 * 4 + j;
          if (kv > qq) sacc[nf][j] = -3.0e38f;
        }
      }
    }
#pragma unroll
    for (int j = 0; j < 4; ++j) {
      float v = fmaxf(fmaxf(sacc[0][j], sacc[1][j]), fmaxf(sacc[2][j], sacc[3][j]));
      v = fmaxf(v, __shfl_xor(v, 1));
      v = fmaxf(v, __shfl_xor(v, 2));
      v = fmaxf(v, __shfl_xor(v, 4));
      v = fmaxf(v, __shfl_xor(v, 8));
      float mn = fmaxf(mrow[j], v);
      float f = __expf(mrow[j] - mn);
      mrow[j] = mn;
      float rs = 0.f;
#pragma unroll
      for (int nf = 0; nf < 4; ++nf) {
        float p = __expf(sacc[nf][j] - mn);
        sacc[nf][j] = p;
        rs += p;
      }
      rs += __shfl_xor(rs, 1);
      rs += __shfl_xor(rs, 2);
      rs += __shfl_xor(rs, 4);
      rs += __shfl_xor(rs, 8);
      lrow[j] = lrow[j] * f + rs;
#pragma unroll
      for (int nf = 0; nf < 8; ++nf) acc_o[nf][j] *= f;
    }
    bf16* pw = &Pl[w][0];
#pragma unroll
    for (int nf = 0; nf < 4; ++nf) {
#pragma unroll
      for (int j = 0; j < 4; ++j) {
        int qq = g4 * 4 + j;
        int kv = nf * 16 + r16;
        pw[qq * 64 + (kv ^ ((qq & 7) << 3))] = (bf16)sacc[nf][j];
      }
    }
    // Pl[w] is wave-private: hardware lgkmcnt ordering suffices, no barrier.
#pragma unroll
    for (int ks2 = 0; ks2 < 2; ++ks2) {
      int qrow = r16;
      bf16x8 pf = *(const bf16x8*)&pw[qrow * 64 + ((((ks2 << 2) | g4)) ^ (qrow & 7)) * 8];
#pragma unroll
      for (int nf = 0; nf < 8; ++nf) {
        int row = nf * 16 + r16;
        bf16x8 vf = *(const bf16x8*)&vsb[row * 64 + ((((ks2 << 2) | g4)) ^ (row & 7)) * 8];
        acc_o[nf] = mfma16(pf, vf, acc_o[nf]);
      }
    }
    __builtin_amdgcn_s_barrier();   // all waves done with buf[cur] before overwrite
    cur ^= 1;
  }
  epilogue(qbase);
}

// ---------------- launch ----------------
// Workspace layout, peak 134.3 MB (phases alias; offsets in bytes):
//   cnts  : 0        (256 B)   inv0 : 4096 (16 KB)   inv1 : 20480 (16 KB)
//   h2    : 36864    (16,777,216) -> ends 16,814,080
//   R = 16,814,080 — shared phase-A / phase-B region:
//   phase A: res1 f32 @R+0 (33.5M) | hbuf @R+33.6M (16.8M, reused attnb) |
//     wqkvT @R+50.3M (12.6M, reused woT) | qkvb bf16 @R+62.9M (25.2M) |
//     qr @R+88.1M | kr @R+104.9M | vtmp @R+109.1M | vT @R+113.2M (end R+117.4M)
//     obuf f32 @R+62.9M (33.5M, overlays dead qkvb+qr-head)
//   phase B: guT @R+0 (45.1M) | dT @R+45.1M (22.5M) | X @R+67.6M (45.1M)
extern "C" void kernel_launch(void* const* d_in, const int* in_sizes, int n_in,
                              void* d_out, int out_size, void* d_ws, size_t ws_size,
                              hipStream_t stream) {
  (void)in_sizes; (void)n_in; (void)out_size; (void)ws_size;
  const int*   positions = (const int*)d_in[0];
  const float* hidden    = (const float*)d_in[1];
  const float* residual  = (const float*)d_in[2];
  const unsigned char* mask_raw = (const unsigned char*)d_in[3];
  const float* w_in_ln   = (const float*)d_in[4];
  const float* w_post_ln = (const float*)d_in[5];
  const float* wqkv      = (const float*)d_in[6];
  const float* bqkv      = (const float*)d_in[7];
  const float* wo        = (const float*)d_in[8];
  const float* mlp_gate  = (const float*)d_in[9];
  const float* mlp_up    = (const float*)d_in[10];
  const float* mlp_down  = (const float*)d_in[11];
  const float* gen_gate  = (const float*)d_in[12];
  const float* gen_up    = (const float*)d_in[13];
  const float* gen_down  = (const float*)d_in[14];
  float* out_f = (float*)d_out;
  float* res2_out = out_f + OUT_ELEMS;

  char* wsb = (char*)d_ws;
  int*  cnts = (int*)wsb;                                   // 256 B
  int*  inv0 = (int*)(wsb + 4096);                          // 16 KB
  int*  inv1 = (int*)(wsb + 20480);                         // 16 KB
  bf16* h2   = (bf16*)(wsb + 36864);                        // 16,777,216
  char* R    = wsb + 16814080;
  // phase A
  float* res1  = (float*)(R);                               // 33,554,432
  bf16*  hbuf  = (bf16*)(R + 33554432);                     // 16,777,216
  bf16*  wqkvT = (bf16*)(R + 50331648);                     // 12,582,912
  bf16*  qkvb  = (bf16*)(R + 62914560);                     // 25,165,824
  bf16*  qr    = (bf16*)(R + 88080384);                     // 16,777,216
  bf16*  kr    = (bf16*)(R + 104857600);                    //  4,194,304
  bf16*  vtmp  = (bf16*)(R + 109051904);                    //  4,194,304
  bf16*  vT    = (bf16*)(R + 113246208);                    //  4,194,304
  bf16*  attnb = hbuf;
  bf16*  woT   = wqkvT;
  float* obuf  = (float*)(R + 62914560);
  // phase B
  bf16* guT = (bf16*)(R);                                   // 45,088,768
  bf16* dT  = (bf16*)(R + 45088768);                        // 22,544,384
  bf16* X   = (bf16*)(R + 67633152);                        // 45,088,768

  dim3 tb(32, 8);

  // ---- mask scan (canon + prefix + inverse perms) ----
  mask_scan<<<1, 256, 0, stream>>>(mask_raw, inv0, inv1, cnts);

  // ---- phase A ----
  add_rmsnorm<<<TOK, 256, 0, stream>>>(hidden, residual, w_in_ln, res1, hbuf);
  transpose_f32_bf16<<<dim3(NQKV / 32, DM / 32), tb, 0, stream>>>(wqkv, wqkvT, DM, NQKV);
  gemm_bt<5, 0><<<dim3(NQKV / 128, TOK / 128), 256, 0, stream>>>(
      hbuf, wqkvT, qkvb, bqkv, nullptr, nullptr, TOK, NQKV, DM);
  rope_split<<<dim3(TOK, 6), 256, 0, stream>>>(qkvb, positions, qr, kr, vtmp);
  transpose_bf16_k<<<dim3(HD / 32, LL / 32, BB * KH), tb, 0, stream>>>(vtmp, vT, LL, HD);
  attn_kernel<<<dim3(NT / 2, BB * HH), 256, 0, stream>>>(qr, kr, vT, attnb);
  transpose_f32_bf16<<<dim3(DM / 32, DM / 32), tb, 0, stream>>>(wo, woT, DM, DM);
  gemm_bt<0, 0><<<dim3(DM / 128, TOK / 128), 256, 0, stream>>>(
      attnb, woT, obuf, nullptr, nullptr, nullptr, TOK, DM, DM);
  add_rmsnorm<<<TOK, 256, 0, stream>>>(obuf, res1, w_post_ln, res2_out, h2);

  // ---- phase B: underlying MLP (tokens with mask==0, compacted) ----
  transpose_f32_bf16<<<dim3(NI / 32, DM / 32), tb, 0, stream>>>(mlp_gate, guT, DM, NI);
  transpose_f32_bf16<<<dim3(NI / 32, DM / 32), tb, 0, stream>>>(mlp_up, guT + (size_t)NI * DM, DM, NI);
  transpose_f32_bf16<<<dim3(DM / 32, NI / 32), tb, 0, stream>>>(mlp_down, dT, NI, DM);
  gemm_bt<2, 1><<<dim3(NI / 128, TOK / 128), 256, 0, stream>>>(
      h2, guT, X, nullptr, inv0, cnts + 0, TOK, NI, DM);
  gemm_bt<4, 1><<<dim3(NI / 128, TOK / 128), 256, 0, stream>>>(
      h2, guT + (size_t)NI * DM, X, nullptr, inv0, cnts + 0, TOK, NI, DM);
  gemm_bt<6, 0><<<dim3(DM / 128, TOK / 128), 256, 0, stream>>>(
      X, dT, out_f, nullptr, inv0, cnts + 0, TOK, DM, NI);

  // ---- phase B: gen MLP (tokens with mask==1, compacted) ----
  transpose_f32_bf16<<<dim3(NI / 32, DM / 32), tb, 0, stream>>>(gen_gate, guT, DM, NI);
  transpose_f32_bf16<<<dim3(NI / 32, DM / 32), tb, 0, stream>>>(gen_up, guT + (size_t)NI * DM, DM, NI);
  transpose_f32_bf16<<<dim3(DM / 32, NI / 32), tb, 0, stream>>>(gen_down, dT, NI, DM);
  gemm_bt<2, 1><<<dim3(NI / 128, TOK / 128), 256, 0, stream>>>(
      h2, guT, X, nullptr, inv1, cnts + 2, TOK, NI, DM);
  gemm_bt<4, 1><<<dim3(NI / 128, TOK / 128), 256, 0, stream>>>(
      h2, guT + (size_t)NI * DM, X, nullptr, inv1, cnts + 2, TOK, NI, DM);
  gemm_bt<6, 0><<<dim3(DM / 128, TOK / 128), 256, 0, stream>>>(
      X, dT, out_f, nullptr, inv1, cnts + 2, TOK, DM, NI);
}